// Round 11
// baseline (2376.807 us; speedup 1.0000x reference)
//
#include <hip/hip_runtime.h>
#include <hip/hip_bf16.h>

typedef unsigned short u16;
typedef unsigned int u32;
typedef unsigned long long u64;
typedef short bf16x8 __attribute__((ext_vector_type(8)));
typedef float f32x4 __attribute__((ext_vector_type(4)));

#define AS1C(p) ((const __attribute__((address_space(1))) void*)(p))
#define AS3(p)  ((__attribute__((address_space(3))) void*)(p))

__device__ __forceinline__ u16 f2bf(float f) {
    union { float f; unsigned u; } v; v.f = f;
    unsigned x = v.u;
    unsigned r = (x + 0x7FFFu + ((x >> 16) & 1u)) >> 16;   // RNE
    return (u16)r;
}
__device__ __forceinline__ void st_atomic_u32(u32* p, u32 v) {
    __hip_atomic_store(p, v, __ATOMIC_RELAXED, __HIP_MEMORY_SCOPE_AGENT);
}
__device__ __forceinline__ u32 ld_atomic_u32(const u32* p) {
    return __hip_atomic_load(p, __ATOMIC_RELAXED, __HIP_MEMORY_SCOPE_AGENT);
}

// transpose+cvt tile: in f32[R][C] -> out bf16[c][r]
__device__ __forceinline__ void tpose_dev(float (*tile)[33],
        const float* __restrict__ in, u16* __restrict__ out,
        int R, int C, int outR, int ldO, int bx, int by) {
    int c0 = bx * 32, r0 = by * 32;
    int tx = threadIdx.x & 31, ty = threadIdx.x >> 5;
#pragma unroll
    for (int yy = 0; yy < 4; ++yy) {
        int r = r0 + ty + yy * 8, cc = c0 + tx;
        tile[ty + yy * 8][tx] = (r < R && cc < C) ? in[(size_t)r * C + cc] : 0.f;
    }
    __syncthreads();
#pragma unroll
    for (int yy = 0; yy < 4; ++yy) {
        int c = c0 + ty + yy * 8, r = r0 + tx;
        if (c < outR && r < ldO) out[(size_t)c * ldO + r] = f2bf(tile[tx][ty + yy * 8]);
    }
    __syncthreads();
}

// ---------- K1: fused prep (gather + ALL transposes incl. W_lin + cvts + zeroing) ----------
__global__ __launch_bounds__(256) void prep(
    const int* __restrict__ tokens, const float* __restrict__ emb, u16* __restrict__ xemb,
    const float* __restrict__ W_ih_f, u16* __restrict__ WT_ihf,
    const float* __restrict__ W_ih_b, u16* __restrict__ WT_ihb,
    const float* __restrict__ W_hh_f, u16* __restrict__ WT_hhf,
    const float* __restrict__ W_hh_b, u16* __restrict__ WT_hhb,
    const float* __restrict__ W_proj_f, u16* __restrict__ WprojTf,
    const float* __restrict__ W_proj_b, u16* __restrict__ WprojTb,
    u16* __restrict__ WprojAf, u16* __restrict__ WprojAb,
    const float* __restrict__ W_lin, u16* __restrict__ WT_lin,
    u64* __restrict__ htagG, u64* __restrict__ htagL,
    u32* __restrict__ ctr, u32* __restrict__ xccmap)
{
    __shared__ float tile[32][33];
    int bid = blockIdx.x;
    int tid = threadIdx.x;
    if (bid < 2048) {
        int tok = tokens[bid];
        const float* src = emb + (size_t)tok * 300;
        u16* dst = xemb + (size_t)bid * 320;
        int c = tid;
        if (c < 320) dst[c] = (c < 300) ? f2bf(src[c]) : (u16)0;
        c += 256;
        if (c < 320) dst[c] = (c < 300) ? f2bf(src[c]) : (u16)0;
        return;
    }
    bid -= 2048;
    if (bid < 640)  { tpose_dev(tile, W_ih_f, WT_ihf, 300, 2048, 2048, 320, bid % 64, bid / 64); return; }
    bid -= 640;
    if (bid < 640)  { tpose_dev(tile, W_ih_b, WT_ihb, 300, 2048, 2048, 320, bid % 64, bid / 64); return; }
    bid -= 640;
    if (bid < 1024) { tpose_dev(tile, W_hh_f, WT_hhf, 512, 2048, 2048, 512, bid % 64, bid / 64); return; }
    bid -= 1024;
    if (bid < 1024) { tpose_dev(tile, W_hh_b, WT_hhb, 512, 2048, 2048, 512, bid % 64, bid / 64); return; }
    bid -= 1024;
    if (bid < 256)  { tpose_dev(tile, W_proj_f, WprojTf, 512, 512, 512, 512, bid % 16, bid / 16); return; }
    bid -= 256;
    if (bid < 256)  { tpose_dev(tile, W_proj_b, WprojTb, 512, 512, 512, 512, bid % 16, bid / 16); return; }
    bid -= 256;
    if (bid < 512)  { int i = bid * 512 + tid; WprojAf[i] = f2bf(W_proj_f[i]); WprojAf[i + 256] = f2bf(W_proj_f[i + 256]); return; }
    bid -= 512;
    if (bid < 512)  { int i = bid * 512 + tid; WprojAb[i] = f2bf(W_proj_b[i]); WprojAb[i + 256] = f2bf(W_proj_b[i + 256]); return; }
    bid -= 512;
    if (bid < 25152) { tpose_dev(tile, W_lin, WT_lin, 512, 50257, 50304, 512, bid % 1572, bid / 1572); return; }
    // zero both htag buffers + counters + xccmap — must run every call (no harness re-poison)
    for (int i = tid; i < 2 * 2 * 4 * 256; i += 256) { htagG[i] = 0ull; htagL[i] = 0ull; }
    if (tid < 64) { ctr[tid] = 0; xccmap[tid] = 0; }
}

// ---------- GEMM body: C[m0.., n0..] 128x128 tile of A[M,K] @ BT[N,K]^T (+bias) ----------
// m97 structure: global_load_lds dwordx4, src-side XOR pre-swizzle chunk^=(row&3)
// matched on swizzled ds_read_b128 (both-sides-or-neither).
struct GemmJob {
    const u16* A; const u16* BT; float* Cf; u16* Cb; const float* bias;
    int M, Nreal, K, ldA, ldB, ldC, arev, orev, orow_base;
};

__device__ __forceinline__ void gemm_body(const GemmJob& j, int m0, int n0,
                                          char* As, char* Bs, int atomicCb) {
    const int tid = threadIdx.x;
    const int lane = tid & 63;
    const int wid = tid >> 6;
    const int wr = wid >> 1, wc = wid & 1;

    f32x4 zero4 = {0.f, 0.f, 0.f, 0.f};
    f32x4 acc[4][4];
#pragma unroll
    for (int i = 0; i < 4; ++i)
#pragma unroll
        for (int jx = 0; jx < 4; ++jx) acc[i][jx] = zero4;

    const int kIters = j.K >> 5;
    const int l15 = lane & 15, kg = lane >> 4;

    const int srow0 = wid * 32 + (lane >> 2);
    const int srow1 = srow0 + 16;
    const int c0 = (lane & 3) ^ (srow0 & 3);
    const int c1 = (lane & 3) ^ (srow1 & 3);
    int ar0 = m0 + srow0, ar1 = m0 + srow1;
    if (j.arev) {
        ar0 = (ar0 & ~511) | (511 - (ar0 & 511));
        ar1 = (ar1 & ~511) | (511 - (ar1 & 511));
    }
    const u16* ga0 = j.A + (size_t)ar0 * j.ldA + c0 * 8;
    const u16* ga1 = j.A + (size_t)ar1 * j.ldA + c1 * 8;
    const u16* gb0 = j.BT + (size_t)(n0 + srow0) * j.ldB + c0 * 8;
    const u16* gb1 = j.BT + (size_t)(n0 + srow1) * j.ldB + c1 * 8;
    char* ldsA0 = As + wid * 2048;
    char* ldsA1 = As + wid * 2048 + 1024;
    char* ldsB0 = Bs + wid * 2048;
    char* ldsB1 = Bs + wid * 2048 + 1024;

    for (int kt = 0; kt < kIters; ++kt) {
        const int k0 = kt * 32;
        __builtin_amdgcn_global_load_lds(AS1C(ga0 + k0), AS3(ldsA0), 16, 0, 0);
        __builtin_amdgcn_global_load_lds(AS1C(ga1 + k0), AS3(ldsA1), 16, 0, 0);
        __builtin_amdgcn_global_load_lds(AS1C(gb0 + k0), AS3(ldsB0), 16, 0, 0);
        __builtin_amdgcn_global_load_lds(AS1C(gb1 + k0), AS3(ldsB1), 16, 0, 0);
        __syncthreads();

        bf16x8 af[4], bfr[4];
#pragma unroll
        for (int mt = 0; mt < 4; ++mt) {
            int r = wr * 64 + mt * 16 + l15;
            af[mt] = *(const bf16x8*)(As + r * 64 + ((kg ^ (r & 3)) * 16));
        }
#pragma unroll
        for (int nt = 0; nt < 4; ++nt) {
            int r = wc * 64 + nt * 16 + l15;
            bfr[nt] = *(const bf16x8*)(Bs + r * 64 + ((kg ^ (r & 3)) * 16));
        }
#pragma unroll
        for (int mt = 0; mt < 4; ++mt)
#pragma unroll
            for (int nt = 0; nt < 4; ++nt)
                acc[mt][nt] = __builtin_amdgcn_mfma_f32_16x16x32_bf16(af[mt], bfr[nt], acc[mt][nt], 0, 0, 0);
        __syncthreads();
    }

#pragma unroll
    for (int nt = 0; nt < 4; ++nt) {
        int col = n0 + wc * 64 + nt * 16 + l15;
        float bv = (j.bias != nullptr && col < j.Nreal) ? j.bias[col] : 0.f;
#pragma unroll
        for (int mt = 0; mt < 4; ++mt) {
#pragma unroll
            for (int jx = 0; jx < 4; ++jx) {
                int m = m0 + wr * 64 + mt * 16 + kg * 4 + jx;
                int om = j.orev ? ((m & ~511) | (511 - (m & 511))) : m;
                om += j.orow_base;
                float v = acc[mt][nt][jx] + bv;
                if (atomicCb) {
                    float pv = __shfl_down(v, 1);
                    if ((l15 & 1) == 0 && col < j.Nreal)
                        st_atomic_u32((u32*)(j.Cb + (size_t)om * j.ldC + col),
                                      (u32)f2bf(v) | ((u32)f2bf(pv) << 16));
                } else if (col < j.Nreal) {
                    if (j.Cf) j.Cf[(size_t)om * j.ldC + col] = v;
                    else      j.Cb[(size_t)om * j.ldC + col] = f2bf(v);
                }
            }
        }
    }
}

__global__ __launch_bounds__(256) void gemm_multi4(GemmJob j0, GemmJob j1, GemmJob j2, GemmJob j3) {
    __shared__ char pool[16384];
    GemmJob j = (blockIdx.z == 0) ? j0 : (blockIdx.z == 1) ? j1 : (blockIdx.z == 2) ? j2 : j3;
    if ((int)blockIdx.y * 128 >= j.M) return;
    gemm_body(j, blockIdx.y * 128, blockIdx.x * 128, pool, pool + 8192, 0);
}

// ---------- K5: mega-kernel: rec (XCC-verified local/LLC sync) + proj/logits chasers ----------
// Role map over first 256 bids (R8 layout; bid%8 -> XCD round-robin heuristic):
//   mod8==0 -> rec fwd blk=bid>>3; mod8==1 -> rec bwd; mod8 2..5 -> proj; 6..7 -> early logits.
// bids >=256 -> remaining logits chasers.
// h-exchange: producers dual-publish each tagged u64 (plain store -> own XCD L2, and
// agent-scope atomic -> LLC). Each rec block reads HW_REG_XCC_ID and publishes it to
// xccmap; each consumer thread polls the LOCAL buffer (sc0) iff GROUND TRUTH says its
// producer shares its XCD, else the proven LLC path (sc0 sc1). 128-iter timeout with
// permanent demotion guards liveness (demoted thread = R7 behavior). Tag+payload share
// one 8B word, so any tag match is genuine regardless of path.
__global__ __launch_bounds__(256) void lstm_fused(
    const float* __restrict__ Wc_f, const float* __restrict__ Wc_b,
    const float* __restrict__ xp_f, const float* __restrict__ xp_b,
    u64* __restrict__ htagG, u64* __restrict__ htagL,
    u16* __restrict__ hpre_f, u16* __restrict__ hpre_b,
    const u16* __restrict__ WT_lin,
    const u16* __restrict__ WprojTf, const u16* __restrict__ WprojTb,
    u16* __restrict__ hall, const float* __restrict__ b_lin,
    float* __restrict__ out, u32* __restrict__ ctr, u32* __restrict__ xccmap)
{
    __shared__ char pool[16384];
    const int tid = threadIdx.x;
    const int bidx = blockIdx.x;

    int dir = 0, blk = 0;
    {
        int lid = -1;
        if (bidx < 256) {
            int mod8 = bidx & 7, grp = bidx >> 3;
            if (mod8 >= 6) lid = (mod8 - 6) * 32 + grp;            // 64 early logits
            else if (mod8 >= 2) {                                  // 128 proj chasers
                int pid = (mod8 - 2) * 32 + grp;
                int pdir = pid >> 6, r = pid & 63, y = r >> 2, x = r & 3;
                int m0 = y * 128, n0 = x * 128;
                if (tid == 0) {
                    while (ld_atomic_u32(&ctr[8 + pdir * 4 + (y & 3)]) < 32u) __builtin_amdgcn_s_sleep(32);
                }
                __syncthreads();
                GemmJob j = { pdir ? hpre_b : hpre_f, pdir ? WprojTb : WprojTf, nullptr, hall, nullptr,
                              2048, 512, 512, 512, 512, 512, 0, pdir ? 1 : 0, pdir ? 2048 : 0 };
                gemm_body(j, m0, n0, pool, pool + 8192, 1);
                asm volatile("s_waitcnt vmcnt(0)" ::: "memory");
                __syncthreads();
                if (tid == 0) {
                    int obrow = j.orow_base + (j.orev ? ((m0 & ~511) | (511 - ((m0 + 127) & 511))) : m0);
                    __hip_atomic_fetch_add(&ctr[16 + (obrow >> 7)], 1u, __ATOMIC_RELAXED, __HIP_MEMORY_SCOPE_AGENT);
                }
                return;
            } else { dir = mod8; blk = grp; }                      // rec block
        } else lid = 64 + (bidx - 256);

        if (lid >= 0) {     // logits chaser, ordered by availability chunk
            int cid = lid / (393 * 8), rr = lid % (393 * 8), bi = rr / 393, x = rr % 393;
            int band = (bi < 4) ? (bi * 4 + cid) : (16 + (bi - 4) * 4 + (3 - cid));
            if (tid == 0) {
                while (ld_atomic_u32(&ctr[16 + band]) < 4u) __builtin_amdgcn_s_sleep(127);
            }
            __syncthreads();
            GemmJob j = { hall, WT_lin, out, nullptr, b_lin,
                          4096, 50257, 512, 512, 512, 50257, 0, 0, 0 };
            gemm_body(j, band * 128, x * 128, pool, pool + 8192, 0);
            return;
        }
    }

    // ---------------- rec block ----------------
    __builtin_amdgcn_s_setprio(1);
    u16 (*hlds)[4][520] = (u16(*)[4][520])pool;    // [parity][b][hu(512)+pad], 8320 B

    const int lane = tid & 63;
    const int w = tid >> 6;            // wave 0..3
    const int l15 = lane & 15;
    const int kg = lane >> 4;
    const int gate = l15 & 3;          // lane's gate: 0=i 1=f 2=g 3=o
    const int hloc = w * 4 + (l15 >> 2);   // hu within block's 16

    const float* wcsrc = dir ? Wc_b : Wc_f;
    const float* xp    = dir ? xp_b : xp_f;
    u16* hpre          = dir ? hpre_b : hpre_f;
    u64* htg           = htagG + (size_t)dir * 2 * 4 * 256;   // [slot][b][256 words]
    u64* htl           = htagL + (size_t)dir * 2 * 4 * 256;

    // ground-truth XCD identification
    u32 myxcc;
    asm volatile("s_getreg_b32 %0, hwreg(HW_REG_XCC_ID)" : "=s"(myxcc));
    if (tid == 0) st_atomic_u32(&xccmap[dir * 32 + blk], myxcc + 1u);

    // Wc B-frags, column-permuted: col = gate*512 + blk*16 + hloc
    bf16x8 wcf[16];
    {
        const int wccol = gate * 512 + blk * 16 + hloc;
#pragma unroll
        for (int ks = 0; ks < 16; ++ks) {
            bf16x8 wv;
#pragma unroll
            for (int e = 0; e < 8; ++e) {
                int k = ks * 32 + kg * 8 + e;
                wv[e] = (short)f2bf(wcsrc[(size_t)k * 2048 + wccol]);
            }
            wcf[ks] = wv;
        }
    }

    // my producer's XCD (producer of word tid is rec block tid>>3 of this direction)
    bool loc;
    {
        u32 pxcc;
        const u32* pm = &xccmap[dir * 32 + (tid >> 3)];
        while ((pxcc = ld_atomic_u32(pm)) == 0u) __builtin_amdgcn_s_sleep(1);
        loc = (pxcc == myxcc + 1u);
    }

    const bf16x8 zero8 = {0, 0, 0, 0, 0, 0, 0, 0};
    float cst[4] = {0.f, 0.f, 0.f, 0.f};     // cell state (gate-0 lanes)

    for (int t = 0; t < 512; ++t) {
        // xp loads (per-lane gate/hu column)
        float xpv[4];
        {
            const float* xb = xp + (size_t)t * 2048 + gate * 512 + blk * 16 + hloc;
#pragma unroll
            for (int j = 0; j < 4; ++j) xpv[j] = xb[(size_t)j * 512 * 2048];
        }
        {   // tagged poll: 4 words/thread (one per batch row); local-L2 or LLC per ground truth
            const u32 target = (u32)t;
            u64 w0, w1, w2, w3;
            bool got = false;
            if (loc) {
                const u64* s = htl + (size_t)(t & 1) * 4 * 256;
                const u64* q0 = s + tid;
                const u64* q1 = s + 256 + tid;
                const u64* q2 = s + 512 + tid;
                const u64* q3 = s + 768 + tid;
                for (int it = 0; it < 128; ++it) {
                    asm volatile(
                        "global_load_dwordx2 %0, %4, off sc0\n\t"
                        "global_load_dwordx2 %1, %5, off sc0\n\t"
                        "global_load_dwordx2 %2, %6, off sc0\n\t"
                        "global_load_dwordx2 %3, %7, off sc0\n\t"
                        "s_waitcnt vmcnt(0)"
                        : "=&v"(w0), "=&v"(w1), "=&v"(w2), "=&v"(w3)
                        : "v"(q0), "v"(q1), "v"(q2), "v"(q3)
                        : "memory");
                    if (((u32)(w0 >> 32) == target) & ((u32)(w1 >> 32) == target) &
                        ((u32)(w2 >> 32) == target) & ((u32)(w3 >> 32) == target)) { got = true; break; }
                    __builtin_amdgcn_s_sleep(1);
                }
                if (!got) loc = false;   // liveness guard: demote permanently, finish via LLC
            }
            if (!got) {
                const u64* s = htg + (size_t)(t & 1) * 4 * 256;
                const u64* q0 = s + tid;
                const u64* q1 = s + 256 + tid;
                const u64* q2 = s + 512 + tid;
                const u64* q3 = s + 768 + tid;
                for (;;) {
                    asm volatile(
                        "global_load_dwordx2 %0, %4, off sc0 sc1\n\t"
                        "global_load_dwordx2 %1, %5, off sc0 sc1\n\t"
                        "global_load_dwordx2 %2, %6, off sc0 sc1\n\t"
                        "global_load_dwordx2 %3, %7, off sc0 sc1\n\t"
                        "s_waitcnt vmcnt(0)"
                        : "=&v"(w0), "=&v"(w1), "=&v"(w2), "=&v"(w3)
                        : "v"(q0), "v"(q1), "v"(q2), "v"(q3)
                        : "memory");
                    if (((u32)(w0 >> 32) == target) & ((u32)(w1 >> 32) == target) &
                        ((u32)(w2 >> 32) == target) & ((u32)(w3 >> 32) == target)) break;
                    __builtin_amdgcn_s_sleep(1);
                }
            }
            asm volatile("" ::: "memory");
            *(u32*)&hlds[t & 1][0][tid * 2] = (u32)w0;
            *(u32*)&hlds[t & 1][1][tid * 2] = (u32)w1;
            *(u32*)&hlds[t & 1][2][tid * 2] = (u32)w2;
            *(u32*)&hlds[t & 1][3][tid * 2] = (u32)w3;
        }
        __syncthreads();   // SYNC_A — the only per-step barrier

        // 16 MFMA, 2 chains; lane l<16: rows j=0..3 = batch, col l15 = (hu,gate)
        f32x4 a0 = {0, 0, 0, 0}, a1 = {0, 0, 0, 0};
#pragma unroll
        for (int ks = 0; ks < 16; ++ks) {
            bf16x8 a = zero8;
            if (l15 < 4) a = *(const bf16x8*)&hlds[t & 1][l15][ks * 32 + kg * 8];
            if (ks & 1) a1 = __builtin_amdgcn_mfma_f32_16x16x32_bf16(a, wcf[ks], a1, 0, 0, 0);
            else        a0 = __builtin_amdgcn_mfma_f32_16x16x32_bf16(a, wcf[ks], a0, 0, 0, 0);
        }
        f32x4 accs = a0 + a1;

        // per-lane activation of its own gate (fast exp2 forms, saturation-safe)
        float act[4];
#pragma unroll
        for (int j = 0; j < 4; ++j) {
            float x = accs[j] + xpv[j];
            float m = (gate == 2) ? 2.885390082f : -1.442695041f;
            float r = __builtin_amdgcn_rcpf(1.f + __builtin_amdgcn_exp2f(m * x));
            act[j] = (gate == 2) ? (1.f - 2.f * r) : r;
        }
        // in-wave gather onto gate-0 lanes: f, g, o
        const int base = lane & ~3;
        float fv[4], gv[4], ov[4];
#pragma unroll
        for (int j = 0; j < 4; ++j) {
            fv[j] = __shfl(act[j], base + 1);
            gv[j] = __shfl(act[j], base + 2);
            ov[j] = __shfl(act[j], base + 3);
        }
        unsigned hbits[4];
#pragma unroll
        for (int j = 0; j < 4; ++j) {
            float c2 = act[j] * gv[j] + fv[j] * cst[j];   // i*g + f*c (gate-0 lanes)
            cst[j] = c2;
            float th = 1.f - 2.f * __builtin_amdgcn_rcpf(1.f + __builtin_amdgcn_exp2f(2.885390082f * c2));
            hbits[j] = f2bf(ov[j] * th);
        }
        // pack hu-pairs: lane l takes partner l+4 (hu+1)
        unsigned pb4[4];
#pragma unroll
        for (int j = 0; j < 4; ++j) pb4[j] = (unsigned)__shfl((int)hbits[j], (lane + 4) & 63);

        if ((lane & 7) == 0 && lane < 16) {   // lanes 0,8 of each wave publish
            const int word = blk * 8 + w * 2 + (lane >> 3);   // global hu-pair index
            const int slot = (t + 1) & 1;
#pragma unroll
            for (int j = 0; j < 4; ++j) {
                u32 packed = hbits[j] | (pb4[j] << 16);
                u64 val = ((u64)(u32)(t + 1) << 32) | (u64)packed;
                // dual publish: plain store -> own XCD L2 (local path), then LLC (proven path)
                asm volatile("global_store_dwordx2 %0, %1, off"
                             :: "v"(htl + (size_t)(slot * 4 + j) * 256 + word), "v"(val) : "memory");
                __hip_atomic_store(&htg[(size_t)(slot * 4 + j) * 256 + word], val,
                                   __ATOMIC_RELAXED, __HIP_MEMORY_SCOPE_AGENT);
                st_atomic_u32((u32*)&hpre[(size_t)(j * 512 + t) * 512 + word * 2], packed);
            }
        }
        if ((t & 127) == 127) {   // chunk boundary: drain all waves' stores, then progress ctr
            asm volatile("s_waitcnt vmcnt(0)" ::: "memory");
            __syncthreads();
            if (tid == 0)
                __hip_atomic_fetch_add(&ctr[8 + dir * 4 + (t >> 7)], 1u,
                                       __ATOMIC_RELAXED, __HIP_MEMORY_SCOPE_AGENT);
        }
    }
}

// ---------- host ----------
extern "C" void kernel_launch(void* const* d_in, const int* in_sizes, int n_in,
                              void* d_out, int out_size, void* d_ws, size_t ws_size,
                              hipStream_t stream) {
    const int*   tokens   = (const int*)d_in[0];
    const float* emb      = (const float*)d_in[1];
    const float* W_ih_f   = (const float*)d_in[2];
    const float* W_hh_f   = (const float*)d_in[3];
    const float* b_f      = (const float*)d_in[4];
    const float* W_proj_f = (const float*)d_in[5];
    const float* W_ih_b   = (const float*)d_in[6];
    const float* W_hh_b   = (const float*)d_in[7];
    const float* b_b      = (const float*)d_in[8];
    const float* W_proj_b = (const float*)d_in[9];
    const float* W_lin    = (const float*)d_in[10];
    const float* b_lin    = (const float*)d_in[11];
    float* out = (float*)d_out;

    char* ws = (char*)d_ws;
    size_t off = 0;
    auto alloc = [&](size_t bytes) -> char* {
        char* p = ws + off;
        off = (off + bytes + 255) & ~(size_t)255;
        return p;
    };
    u16* xemb     = (u16*)alloc(2048 * 320 * 2);
    u16* WT_ihf   = (u16*)alloc(2048 * 320 * 2);
    u16* WT_ihb   = (u16*)alloc(2048 * 320 * 2);
    u16* WT_hhf   = (u16*)alloc(2048 * 512 * 2);
    u16* WT_hhb   = (u16*)alloc(2048 * 512 * 2);
    u16* WprojTf  = (u16*)alloc(512 * 512 * 2);
    u16* WprojTb  = (u16*)alloc(512 * 512 * 2);
    u16* WprojAf  = (u16*)alloc(512 * 512 * 2);
    u16* WprojAb  = (u16*)alloc(512 * 512 * 2);
    u16* WT_lin   = (u16*)alloc((size_t)50304 * 512 * 2);
    float* xpf    = (float*)alloc((size_t)2048 * 2048 * 4);
    float* xpb    = (float*)alloc((size_t)2048 * 2048 * 4);
    float* Wc32f  = (float*)alloc((size_t)512 * 2048 * 4);
    float* Wc32b  = (float*)alloc((size_t)512 * 2048 * 4);
    u16* hpref    = (u16*)alloc((size_t)2048 * 512 * 2);
    u16* hpreb    = (u16*)alloc((size_t)2048 * 512 * 2);
    u16* hall     = (u16*)alloc((size_t)4096 * 512 * 2);
    u64* htagG    = (u64*)alloc((size_t)2 * 2 * 4 * 256 * 8);
    u64* htagL    = (u64*)alloc((size_t)2 * 2 * 4 * 256 * 8);
    u32* ctr      = (u32*)alloc(64 * 4);
    u32* xccmap   = (u32*)alloc(64 * 4);

    // 1) all prep (incl. W_lin transpose) in one launch
    prep<<<2048 + 640 + 640 + 1024 + 1024 + 256 + 256 + 512 + 512 + 25152 + 1, 256, 0, stream>>>(
        tokens, emb, xemb,
        W_ih_f, WT_ihf, W_ih_b, WT_ihb,
        W_hh_f, WT_hhf, W_hh_b, WT_hhb,
        W_proj_f, WprojTf, W_proj_b, WprojTb,
        WprojAf, WprojAb, W_lin, WT_lin, htagG, htagL, ctr, xccmap);

    // 2) xp (fwd, bwd) + Wc (fwd, bwd) in one z=4 launch
    GemmJob jxf = {xemb, WT_ihf, xpf, nullptr, b_f, 2048, 2048, 320, 320, 320, 2048, 0, 0, 0};
    GemmJob jxb = {xemb, WT_ihb, xpb, nullptr, b_b, 2048, 2048, 320, 320, 320, 2048, 1, 0, 0};
    GemmJob jwf = {WprojAf, WT_hhf, Wc32f, nullptr, nullptr, 512, 2048, 512, 512, 512, 2048, 0, 0, 0};
    GemmJob jwb = {WprojAb, WT_hhb, Wc32b, nullptr, nullptr, 512, 2048, 512, 512, 512, 2048, 0, 0, 0};
    gemm_multi4<<<dim3(16, 16, 4), 256, 0, stream>>>(jxf, jxb, jwf, jwb);

    // 3) mega-kernel: rec (XCC-verified grouped sync) + proj chasers + logits chasers
    lstm_fused<<<256 + 12576 - 64, 256, 0, stream>>>(
        Wc32f, Wc32b, xpf, xpb, htagG, htagL, hpref, hpreb,
        WT_lin, WprojTf, WprojTb, hall, b_lin, out, ctr, xccmap);
}

// Round 12
// 1642.423 us; speedup vs baseline: 1.4471x; 1.4471x over previous
//
#include <hip/hip_runtime.h>
#include <hip/hip_bf16.h>

typedef unsigned short u16;
typedef unsigned int u32;
typedef unsigned long long u64;
typedef short bf16x8 __attribute__((ext_vector_type(8)));
typedef float f32x4 __attribute__((ext_vector_type(4)));

#define AS1C(p) ((const __attribute__((address_space(1))) void*)(p))
#define AS3(p)  ((__attribute__((address_space(3))) void*)(p))

__device__ __forceinline__ u16 f2bf(float f) {
    union { float f; unsigned u; } v; v.f = f;
    unsigned x = v.u;
    unsigned r = (x + 0x7FFFu + ((x >> 16) & 1u)) >> 16;   // RNE
    return (u16)r;
}
__device__ __forceinline__ void st_atomic_u32(u32* p, u32 v) {
    __hip_atomic_store(p, v, __ATOMIC_RELAXED, __HIP_MEMORY_SCOPE_AGENT);
}
__device__ __forceinline__ u32 ld_atomic_u32(const u32* p) {
    return __hip_atomic_load(p, __ATOMIC_RELAXED, __HIP_MEMORY_SCOPE_AGENT);
}

// transpose+cvt tile: in f32[R][C] -> out bf16[c][r]
__device__ __forceinline__ void tpose_dev(float (*tile)[33],
        const float* __restrict__ in, u16* __restrict__ out,
        int R, int C, int outR, int ldO, int bx, int by) {
    int c0 = bx * 32, r0 = by * 32;
    int tx = threadIdx.x & 31, ty = threadIdx.x >> 5;
#pragma unroll
    for (int yy = 0; yy < 4; ++yy) {
        int r = r0 + ty + yy * 8, cc = c0 + tx;
        tile[ty + yy * 8][tx] = (r < R && cc < C) ? in[(size_t)r * C + cc] : 0.f;
    }
    __syncthreads();
#pragma unroll
    for (int yy = 0; yy < 4; ++yy) {
        int c = c0 + ty + yy * 8, r = r0 + tx;
        if (c < outR && r < ldO) out[(size_t)c * ldO + r] = f2bf(tile[tx][ty + yy * 8]);
    }
    __syncthreads();
}

// ---------- K1: fused prep (gather + ALL transposes incl. W_lin + cvts + htag/ctr zero) ----------
__global__ __launch_bounds__(256) void prep(
    const int* __restrict__ tokens, const float* __restrict__ emb, u16* __restrict__ xemb,
    const float* __restrict__ W_ih_f, u16* __restrict__ WT_ihf,
    const float* __restrict__ W_ih_b, u16* __restrict__ WT_ihb,
    const float* __restrict__ W_hh_f, u16* __restrict__ WT_hhf,
    const float* __restrict__ W_hh_b, u16* __restrict__ WT_hhb,
    const float* __restrict__ W_proj_f, u16* __restrict__ WprojTf,
    const float* __restrict__ W_proj_b, u16* __restrict__ WprojTb,
    u16* __restrict__ WprojAf, u16* __restrict__ WprojAb,
    const float* __restrict__ W_lin, u16* __restrict__ WT_lin,
    u64* __restrict__ htag, u32* __restrict__ ctr)
{
    __shared__ float tile[32][33];
    int bid = blockIdx.x;
    int tid = threadIdx.x;
    if (bid < 2048) {
        int tok = tokens[bid];
        const float* src = emb + (size_t)tok * 300;
        u16* dst = xemb + (size_t)bid * 320;
        int c = tid;
        if (c < 320) dst[c] = (c < 300) ? f2bf(src[c]) : (u16)0;
        c += 256;
        if (c < 320) dst[c] = (c < 300) ? f2bf(src[c]) : (u16)0;
        return;
    }
    bid -= 2048;
    if (bid < 640)  { tpose_dev(tile, W_ih_f, WT_ihf, 300, 2048, 2048, 320, bid % 64, bid / 64); return; }
    bid -= 640;
    if (bid < 640)  { tpose_dev(tile, W_ih_b, WT_ihb, 300, 2048, 2048, 320, bid % 64, bid / 64); return; }
    bid -= 640;
    if (bid < 1024) { tpose_dev(tile, W_hh_f, WT_hhf, 512, 2048, 2048, 512, bid % 64, bid / 64); return; }
    bid -= 1024;
    if (bid < 1024) { tpose_dev(tile, W_hh_b, WT_hhb, 512, 2048, 2048, 512, bid % 64, bid / 64); return; }
    bid -= 1024;
    if (bid < 256)  { tpose_dev(tile, W_proj_f, WprojTf, 512, 512, 512, 512, bid % 16, bid / 16); return; }
    bid -= 256;
    if (bid < 256)  { tpose_dev(tile, W_proj_b, WprojTb, 512, 512, 512, 512, bid % 16, bid / 16); return; }
    bid -= 256;
    if (bid < 512)  { int i = bid * 512 + tid; WprojAf[i] = f2bf(W_proj_f[i]); WprojAf[i + 256] = f2bf(W_proj_f[i + 256]); return; }
    bid -= 512;
    if (bid < 512)  { int i = bid * 512 + tid; WprojAb[i] = f2bf(W_proj_b[i]); WprojAb[i + 256] = f2bf(W_proj_b[i + 256]); return; }
    bid -= 512;
    if (bid < 25152) { tpose_dev(tile, W_lin, WT_lin, 512, 50257, 50304, 512, bid % 1572, bid / 1572); return; }
    // zero htag + counters — must run every call (harness does not re-poison)
    for (int i = tid; i < 2 * 2 * 4 * 256; i += 256) htag[i] = 0ull;
    if (tid < 64) ctr[tid] = 0;
}

// ---------- GEMM body: C[m0.., n0..] 128x128 tile of A[M,K] @ BT[N,K]^T (+bias) ----------
// m97 structure: global_load_lds dwordx4, src-side XOR pre-swizzle chunk^=(row&3)
// matched on swizzled ds_read_b128 (both-sides-or-neither).
// thr!=0: bandwidth throttle — s_sleep per K-iter (logits chasers only) to cap the
// instantaneous HBM/fabric rate that inflates the rec sync RTT (R5 vs R7 evidence).
struct GemmJob {
    const u16* A; const u16* BT; float* Cf; u16* Cb; const float* bias;
    int M, Nreal, K, ldA, ldB, ldC, arev, orev, orow_base;
};

__device__ __forceinline__ void gemm_body(const GemmJob& j, int m0, int n0,
                                          char* As, char* Bs, int atomicCb, int thr) {
    const int tid = threadIdx.x;
    const int lane = tid & 63;
    const int wid = tid >> 6;
    const int wr = wid >> 1, wc = wid & 1;

    f32x4 zero4 = {0.f, 0.f, 0.f, 0.f};
    f32x4 acc[4][4];
#pragma unroll
    for (int i = 0; i < 4; ++i)
#pragma unroll
        for (int jx = 0; jx < 4; ++jx) acc[i][jx] = zero4;

    const int kIters = j.K >> 5;
    const int l15 = lane & 15, kg = lane >> 4;

    const int srow0 = wid * 32 + (lane >> 2);
    const int srow1 = srow0 + 16;
    const int c0 = (lane & 3) ^ (srow0 & 3);
    const int c1 = (lane & 3) ^ (srow1 & 3);
    int ar0 = m0 + srow0, ar1 = m0 + srow1;
    if (j.arev) {
        ar0 = (ar0 & ~511) | (511 - (ar0 & 511));
        ar1 = (ar1 & ~511) | (511 - (ar1 & 511));
    }
    const u16* ga0 = j.A + (size_t)ar0 * j.ldA + c0 * 8;
    const u16* ga1 = j.A + (size_t)ar1 * j.ldA + c1 * 8;
    const u16* gb0 = j.BT + (size_t)(n0 + srow0) * j.ldB + c0 * 8;
    const u16* gb1 = j.BT + (size_t)(n0 + srow1) * j.ldB + c1 * 8;
    char* ldsA0 = As + wid * 2048;
    char* ldsA1 = As + wid * 2048 + 1024;
    char* ldsB0 = Bs + wid * 2048;
    char* ldsB1 = Bs + wid * 2048 + 1024;

    for (int kt = 0; kt < kIters; ++kt) {
        if (thr) __builtin_amdgcn_s_sleep(16);   // ~0.43us/iter: halves instantaneous BW
        const int k0 = kt * 32;
        __builtin_amdgcn_global_load_lds(AS1C(ga0 + k0), AS3(ldsA0), 16, 0, 0);
        __builtin_amdgcn_global_load_lds(AS1C(ga1 + k0), AS3(ldsA1), 16, 0, 0);
        __builtin_amdgcn_global_load_lds(AS1C(gb0 + k0), AS3(ldsB0), 16, 0, 0);
        __builtin_amdgcn_global_load_lds(AS1C(gb1 + k0), AS3(ldsB1), 16, 0, 0);
        __syncthreads();

        bf16x8 af[4], bfr[4];
#pragma unroll
        for (int mt = 0; mt < 4; ++mt) {
            int r = wr * 64 + mt * 16 + l15;
            af[mt] = *(const bf16x8*)(As + r * 64 + ((kg ^ (r & 3)) * 16));
        }
#pragma unroll
        for (int nt = 0; nt < 4; ++nt) {
            int r = wc * 64 + nt * 16 + l15;
            bfr[nt] = *(const bf16x8*)(Bs + r * 64 + ((kg ^ (r & 3)) * 16));
        }
#pragma unroll
        for (int mt = 0; mt < 4; ++mt)
#pragma unroll
            for (int nt = 0; nt < 4; ++nt)
                acc[mt][nt] = __builtin_amdgcn_mfma_f32_16x16x32_bf16(af[mt], bfr[nt], acc[mt][nt], 0, 0, 0);
        __syncthreads();
    }

#pragma unroll
    for (int nt = 0; nt < 4; ++nt) {
        int col = n0 + wc * 64 + nt * 16 + l15;
        float bv = (j.bias != nullptr && col < j.Nreal) ? j.bias[col] : 0.f;
#pragma unroll
        for (int mt = 0; mt < 4; ++mt) {
#pragma unroll
            for (int jx = 0; jx < 4; ++jx) {
                int m = m0 + wr * 64 + mt * 16 + kg * 4 + jx;
                int om = j.orev ? ((m & ~511) | (511 - (m & 511))) : m;
                om += j.orow_base;
                float v = acc[mt][nt][jx] + bv;
                if (atomicCb) {
                    float pv = __shfl_down(v, 1);
                    if ((l15 & 1) == 0 && col < j.Nreal)
                        st_atomic_u32((u32*)(j.Cb + (size_t)om * j.ldC + col),
                                      (u32)f2bf(v) | ((u32)f2bf(pv) << 16));
                } else if (col < j.Nreal) {
                    if (j.Cf) j.Cf[(size_t)om * j.ldC + col] = v;
                    else      j.Cb[(size_t)om * j.ldC + col] = f2bf(v);
                }
            }
        }
    }
}

__global__ __launch_bounds__(256) void gemm_multi4(GemmJob j0, GemmJob j1, GemmJob j2, GemmJob j3) {
    __shared__ char pool[16384];
    GemmJob j = (blockIdx.z == 0) ? j0 : (blockIdx.z == 1) ? j1 : (blockIdx.z == 2) ? j2 : j3;
    if ((int)blockIdx.y * 128 >= j.M) return;
    gemm_body(j, blockIdx.y * 128, blockIdx.x * 128, pool, pool + 8192, 0, 0);
}

// ---------- K5: persistent LSTM recurrence + proj/logits chaser mega-kernel (R10 layout) ----------
// blocks 0..63: rec (dir=bid>>5, blk=bid&31 owns 16 hu). Column-permuted Wc so one MFMA
// tile = 4 hu x 4 gates -> gate combine via in-wave __shfl; cell state in registers;
// fast exp2 activations; ONE barrier/step; hlds parity double-buffer.
// h-exchange: proven R3/R7 protocol ONLY (relaxed agent-scope tagged u64, LLC poll).
// blocks 64..191: proj chasers; blocks 192..: logits chasers (throttled gemm_body).
__global__ __launch_bounds__(256) void lstm_fused(
    const float* __restrict__ Wc_f, const float* __restrict__ Wc_b,
    const float* __restrict__ xp_f, const float* __restrict__ xp_b,
    u64* __restrict__ htag,
    u16* __restrict__ hpre_f, u16* __restrict__ hpre_b,
    const u16* __restrict__ WT_lin,
    const u16* __restrict__ WprojTf, const u16* __restrict__ WprojTb,
    u16* __restrict__ hall, const float* __restrict__ b_lin,
    float* __restrict__ out, u32* __restrict__ ctr)
{
    __shared__ char pool[16384];
    const int tid = threadIdx.x;
    int bid = blockIdx.x;

    if (bid >= 64) {
        bid -= 64;
        if (bid < 128) {    // proj chaser: hall tile = hpre @ W_proj (unthrottled)
            int dir = bid >> 6, r = bid & 63, y = r >> 2, x = r & 3;
            int m0 = y * 128, n0 = x * 128;
            if (tid == 0) {
                while (ld_atomic_u32(&ctr[8 + dir * 4 + (y & 3)]) < 32u) __builtin_amdgcn_s_sleep(32);
            }
            __syncthreads();
            GemmJob j = { dir ? hpre_b : hpre_f, dir ? WprojTb : WprojTf, nullptr, hall, nullptr,
                          2048, 512, 512, 512, 512, 512, 0, dir ? 1 : 0, dir ? 2048 : 0 };
            gemm_body(j, m0, n0, pool, pool + 8192, 1, 0);
            asm volatile("s_waitcnt vmcnt(0)" ::: "memory");
            __syncthreads();
            if (tid == 0) {
                int obrow = j.orow_base + (j.orev ? ((m0 & ~511) | (511 - ((m0 + 127) & 511))) : m0);
                __hip_atomic_fetch_add(&ctr[16 + (obrow >> 7)], 1u, __ATOMIC_RELAXED, __HIP_MEMORY_SCOPE_AGENT);
            }
            return;
        }
        bid -= 128;
        {                   // logits chaser, ordered by availability chunk (THROTTLED)
            int cid = bid / (393 * 8), rr = bid % (393 * 8), bi = rr / 393, x = rr % 393;
            int band = (bi < 4) ? (bi * 4 + cid) : (16 + (bi - 4) * 4 + (3 - cid));
            if (tid == 0) {
                while (ld_atomic_u32(&ctr[16 + band]) < 4u) __builtin_amdgcn_s_sleep(127);
            }
            __syncthreads();
            GemmJob j = { hall, WT_lin, out, nullptr, b_lin,
                          4096, 50257, 512, 512, 512, 50257, 0, 0, 0 };
            gemm_body(j, band * 128, x * 128, pool, pool + 8192, 0, 1);
            return;
        }
    }

    // ---------------- rec block ----------------
    __builtin_amdgcn_s_setprio(1);
    u16 (*hlds)[4][520] = (u16(*)[4][520])pool;    // [parity][b][hu(512)+pad], 8320 B

    const int dir = blockIdx.x >> 5;
    const int blk = blockIdx.x & 31;
    const int lane = tid & 63;
    const int w = tid >> 6;            // wave 0..3
    const int l15 = lane & 15;
    const int kg = lane >> 4;
    const int gate = l15 & 3;          // lane's gate: 0=i 1=f 2=g 3=o
    const int hloc = w * 4 + (l15 >> 2);   // hu within block's 16

    const float* wcsrc = dir ? Wc_b : Wc_f;
    const float* xp    = dir ? xp_b : xp_f;
    u16* hpre          = dir ? hpre_b : hpre_f;
    u64* ht            = htag + (size_t)dir * 2 * 4 * 256;   // [slot][b][256 words]

    // Wc B-frags, column-permuted: col = gate*512 + blk*16 + hloc
    bf16x8 wcf[16];
    {
        const int wccol = gate * 512 + blk * 16 + hloc;
#pragma unroll
        for (int ks = 0; ks < 16; ++ks) {
            bf16x8 wv;
#pragma unroll
            for (int e = 0; e < 8; ++e) {
                int k = ks * 32 + kg * 8 + e;
                wv[e] = (short)f2bf(wcsrc[(size_t)k * 2048 + wccol]);
            }
            wcf[ks] = wv;
        }
    }

    const bf16x8 zero8 = {0, 0, 0, 0, 0, 0, 0, 0};
    float cst[4] = {0.f, 0.f, 0.f, 0.f};     // cell state (gate-0 lanes)

    for (int t = 0; t < 512; ++t) {
        // xp loads (per-lane gate/hu column)
        float xpv[4];
        {
            const float* xb = xp + (size_t)t * 2048 + gate * 512 + blk * 16 + hloc;
#pragma unroll
            for (int j = 0; j < 4; ++j) xpv[j] = xb[(size_t)j * 512 * 2048];
        }
        {   // tagged poll: 4 words/thread (one per batch row), proven LLC protocol
            const u64* src = ht + (size_t)(t & 1) * 4 * 256;
            const u64* p0 = src + tid;
            const u64* p1 = src + 256 + tid;
            const u64* p2 = src + 512 + tid;
            const u64* p3 = src + 768 + tid;
            const u32 target = (u32)t;
            u64 w0, w1, w2, w3;
            for (;;) {
                asm volatile(
                    "global_load_dwordx2 %0, %4, off sc0 sc1\n\t"
                    "global_load_dwordx2 %1, %5, off sc0 sc1\n\t"
                    "global_load_dwordx2 %2, %6, off sc0 sc1\n\t"
                    "global_load_dwordx2 %3, %7, off sc0 sc1\n\t"
                    "s_waitcnt vmcnt(0)"
                    : "=&v"(w0), "=&v"(w1), "=&v"(w2), "=&v"(w3)
                    : "v"(p0), "v"(p1), "v"(p2), "v"(p3)
                    : "memory");
                if (((u32)(w0 >> 32) == target) & ((u32)(w1 >> 32) == target) &
                    ((u32)(w2 >> 32) == target) & ((u32)(w3 >> 32) == target)) break;
                __builtin_amdgcn_s_sleep(1);
            }
            asm volatile("" ::: "memory");
            *(u32*)&hlds[t & 1][0][tid * 2] = (u32)w0;
            *(u32*)&hlds[t & 1][1][tid * 2] = (u32)w1;
            *(u32*)&hlds[t & 1][2][tid * 2] = (u32)w2;
            *(u32*)&hlds[t & 1][3][tid * 2] = (u32)w3;
        }
        __syncthreads();   // SYNC_A — the only per-step barrier

        // 16 MFMA, 2 chains; lane l<16: rows j=0..3 = batch, col l15 = (hu,gate)
        f32x4 a0 = {0, 0, 0, 0}, a1 = {0, 0, 0, 0};
#pragma unroll
        for (int ks = 0; ks < 16; ++ks) {
            bf16x8 a = zero8;
            if (l15 < 4) a = *(const bf16x8*)&hlds[t & 1][l15][ks * 32 + kg * 8];
            if (ks & 1) a1 = __builtin_amdgcn_mfma_f32_16x16x32_bf16(a, wcf[ks], a1, 0, 0, 0);
            else        a0 = __builtin_amdgcn_mfma_f32_16x16x32_bf16(a, wcf[ks], a0, 0, 0, 0);
        }
        f32x4 accs = a0 + a1;

        // per-lane activation of its own gate (fast exp2 forms, saturation-safe)
        float act[4];
#pragma unroll
        for (int j = 0; j < 4; ++j) {
            float x = accs[j] + xpv[j];
            float m = (gate == 2) ? 2.885390082f : -1.442695041f;
            float r = __builtin_amdgcn_rcpf(1.f + __builtin_amdgcn_exp2f(m * x));
            act[j] = (gate == 2) ? (1.f - 2.f * r) : r;
        }
        // in-wave gather onto gate-0 lanes: f, g, o
        const int base = lane & ~3;
        float fv[4], gv[4], ov[4];
#pragma unroll
        for (int j = 0; j < 4; ++j) {
            fv[j] = __shfl(act[j], base + 1);
            gv[j] = __shfl(act[j], base + 2);
            ov[j] = __shfl(act[j], base + 3);
        }
        unsigned hbits[4];
#pragma unroll
        for (int j = 0; j < 4; ++j) {
            float c2 = act[j] * gv[j] + fv[j] * cst[j];   // i*g + f*c (gate-0 lanes)
            cst[j] = c2;
            float th = 1.f - 2.f * __builtin_amdgcn_rcpf(1.f + __builtin_amdgcn_exp2f(2.885390082f * c2));
            hbits[j] = f2bf(ov[j] * th);
        }
        // pack hu-pairs: lane l takes partner l+4 (hu+1)
        unsigned pb4[4];
#pragma unroll
        for (int j = 0; j < 4; ++j) pb4[j] = (unsigned)__shfl((int)hbits[j], (lane + 4) & 63);

        if ((lane & 7) == 0 && lane < 16) {   // lanes 0,8 of each wave publish
            const int word = blk * 8 + w * 2 + (lane >> 3);   // global hu-pair index
            const int slot = (t + 1) & 1;
#pragma unroll
            for (int j = 0; j < 4; ++j) {
                u32 packed = hbits[j] | (pb4[j] << 16);
                u64 val = ((u64)(u32)(t + 1) << 32) | (u64)packed;
                __hip_atomic_store(&ht[(size_t)(slot * 4 + j) * 256 + word], val,
                                   __ATOMIC_RELAXED, __HIP_MEMORY_SCOPE_AGENT);
                st_atomic_u32((u32*)&hpre[(size_t)(j * 512 + t) * 512 + word * 2], packed);
            }
        }
        if ((t & 127) == 127) {   // chunk boundary: drain all waves' stores, then progress ctr
            asm volatile("s_waitcnt vmcnt(0)" ::: "memory");
            __syncthreads();
            if (tid == 0)
                __hip_atomic_fetch_add(&ctr[8 + dir * 4 + (t >> 7)], 1u,
                                       __ATOMIC_RELAXED, __HIP_MEMORY_SCOPE_AGENT);
        }
    }
}

// ---------- host ----------
extern "C" void kernel_launch(void* const* d_in, const int* in_sizes, int n_in,
                              void* d_out, int out_size, void* d_ws, size_t ws_size,
                              hipStream_t stream) {
    const int*   tokens   = (const int*)d_in[0];
    const float* emb      = (const float*)d_in[1];
    const float* W_ih_f   = (const float*)d_in[2];
    const float* W_hh_f   = (const float*)d_in[3];
    const float* b_f      = (const float*)d_in[4];
    const float* W_proj_f = (const float*)d_in[5];
    const float* W_ih_b   = (const float*)d_in[6];
    const float* W_hh_b   = (const float*)d_in[7];
    const float* b_b      = (const float*)d_in[8];
    const float* W_proj_b = (const float*)d_in[9];
    const float* W_lin    = (const float*)d_in[10];
    const float* b_lin    = (const float*)d_in[11];
    float* out = (float*)d_out;

    char* ws = (char*)d_ws;
    size_t off = 0;
    auto alloc = [&](size_t bytes) -> char* {
        char* p = ws + off;
        off = (off + bytes + 255) & ~(size_t)255;
        return p;
    };
    u16* xemb     = (u16*)alloc(2048 * 320 * 2);
    u16* WT_ihf   = (u16*)alloc(2048 * 320 * 2);
    u16* WT_ihb   = (u16*)alloc(2048 * 320 * 2);
    u16* WT_hhf   = (u16*)alloc(2048 * 512 * 2);
    u16* WT_hhb   = (u16*)alloc(2048 * 512 * 2);
    u16* WprojTf  = (u16*)alloc(512 * 512 * 2);
    u16* WprojTb  = (u16*)alloc(512 * 512 * 2);
    u16* WprojAf  = (u16*)alloc(512 * 512 * 2);
    u16* WprojAb  = (u16*)alloc(512 * 512 * 2);
    u16* WT_lin   = (u16*)alloc((size_t)50304 * 512 * 2);
    float* xpf    = (float*)alloc((size_t)2048 * 2048 * 4);
    float* xpb    = (float*)alloc((size_t)2048 * 2048 * 4);
    float* Wc32f  = (float*)alloc((size_t)512 * 2048 * 4);
    float* Wc32b  = (float*)alloc((size_t)512 * 2048 * 4);
    u16* hpref    = (u16*)alloc((size_t)2048 * 512 * 2);
    u16* hpreb    = (u16*)alloc((size_t)2048 * 512 * 2);
    u16* hall     = (u16*)alloc((size_t)4096 * 512 * 2);
    u64* htag     = (u64*)alloc((size_t)2 * 2 * 4 * 256 * 8);
    u32* ctr      = (u32*)alloc(64 * 4);

    // 1) all prep (incl. W_lin transpose) in one launch
    prep<<<2048 + 640 + 640 + 1024 + 1024 + 256 + 256 + 512 + 512 + 25152 + 1, 256, 0, stream>>>(
        tokens, emb, xemb,
        W_ih_f, WT_ihf, W_ih_b, WT_ihb,
        W_hh_f, WT_hhf, W_hh_b, WT_hhb,
        W_proj_f, WprojTf, W_proj_b, WprojTb,
        WprojAf, WprojAb, W_lin, WT_lin, htag, ctr);

    // 2) xp (fwd, bwd) + Wc (fwd, bwd) in one z=4 launch
    GemmJob jxf = {xemb, WT_ihf, xpf, nullptr, b_f, 2048, 2048, 320, 320, 320, 2048, 0, 0, 0};
    GemmJob jxb = {xemb, WT_ihb, xpb, nullptr, b_b, 2048, 2048, 320, 320, 320, 2048, 1, 0, 0};
    GemmJob jwf = {WprojAf, WT_hhf, Wc32f, nullptr, nullptr, 512, 2048, 512, 512, 512, 2048, 0, 0, 0};
    GemmJob jwb = {WprojAb, WT_hhb, Wc32b, nullptr, nullptr, 512, 2048, 512, 512, 512, 2048, 0, 0, 0};
    gemm_multi4<<<dim3(16, 16, 4), 256, 0, stream>>>(jxf, jxb, jwf, jwb);

    // 3) mega-kernel: rec + proj chasers + throttled logits chasers (R10 grid)
    lstm_fused<<<64 + 128 + 12576, 256, 0, stream>>>(
        Wc32f, Wc32b, xpf, xpb, htag, hpref, hpreb,
        WT_lin, WprojTf, WprojTb, hall, b_lin, out, ctr);
}